// Round 3
// baseline (122.021 us; speedup 1.0000x reference)
//
#include <hip/hip_runtime.h>

// Problem constants (B=16, C=3, H=W=512)
#define HW_SHIFT 18
#define HW_ (1 << HW_SHIFT)           // 262144
#define NCH 48                         // B*C
#define NTASK (2 * NCH)                // 96: ref-hist and tgt-hist per channel
#define TOTAL (NCH * HW_)              // 12,582,912
#define NBINS 8192                     // 32KB LDS histogram
#define LO_ (-640.0f)
#define HI_ (896.0f)
#define BINW ((HI_ - LO_) / (float)NBINS)
#define INVW ((float)NBINS / (HI_ - LO_))
#define LOSS_BLOCKS 2048

__device__ __forceinline__ float t2i(float x) { return fmaf(x, 127.5f, 127.5f); }

__device__ __forceinline__ int bin_of(float v) {
    int b = (int)((v - LO_) * INVW);
    b = b < 0 ? 0 : b;
    b = b > NBINS - 1 ? NBINS - 1 : b;
    return b;
}

// Bank-spreading involution for the fused scan kernel's LDS arrays:
// XOR low-5 bits with bits 5..9. Contiguous-chunk-per-thread access
// (bin = t*32+i) maps to bank i^(t&31): 2 lanes/bank (free).
__device__ __forceinline__ int sidx(int b) { return b ^ ((b >> 5) & 31); }

// grid = NTASK*bpt blocks of 512. task = blockIdx.x/bpt; which = task/NCH
// (0 = ref/smask, 1 = tgt/tmask); ch = task%NCH. Each block histograms
// HW_/bpt pixels into a 32KB LDS histogram, then plain-stores the partial.
__global__ __launch_bounds__(512) void hist_kernel(
    const float* __restrict__ ref, const float* __restrict__ tgt,
    const float* __restrict__ smask, const float* __restrict__ tmask,
    unsigned* __restrict__ partials, int bpt)
{
    __shared__ unsigned lh[NBINS];
    for (int i = threadIdx.x; i < NBINS; i += 512) lh[i] = 0u;
    __syncthreads();

    int task  = blockIdx.x / bpt;
    int slice = blockIdx.x - task * bpt;
    int which = task / NCH;
    int ch    = task - which * NCH;
    const float* img = which ? tgt : ref;
    const float* msk = which ? tmask : smask;
    int mb = ch / 3;

    const float4* img4 = (const float4*)img + ((size_t)ch << (HW_SHIFT - 2));
    const float4* msk4 = (const float4*)msk + ((size_t)mb << (HW_SHIFT - 2));
    int n4   = (HW_ / 4) / bpt;       // 8192 at bpt=8 (divisible by 1024)
    int base = slice * n4;
    for (int i = threadIdx.x; i < n4; i += 1024) {
        float4 v0 = img4[base + i];
        float4 m0 = msk4[base + i];
        float4 v1 = img4[base + i + 512];
        float4 m1 = msk4[base + i + 512];
        atomicAdd(&lh[bin_of(t2i(v0.x) * m0.x)], 1u);
        atomicAdd(&lh[bin_of(t2i(v0.y) * m0.y)], 1u);
        atomicAdd(&lh[bin_of(t2i(v0.z) * m0.z)], 1u);
        atomicAdd(&lh[bin_of(t2i(v0.w) * m0.w)], 1u);
        atomicAdd(&lh[bin_of(t2i(v1.x) * m1.x)], 1u);
        atomicAdd(&lh[bin_of(t2i(v1.y) * m1.y)], 1u);
        atomicAdd(&lh[bin_of(t2i(v1.z) * m1.z)], 1u);
        atomicAdd(&lh[bin_of(t2i(v1.w) * m1.w)], 1u);
    }
    __syncthreads();
    unsigned* outp = partials + (size_t)blockIdx.x * NBINS;
    for (int i = threadIdx.x; i < NBINS; i += 512) outp[i] = lh[i];
}

// grid = NCH blocks of 256. Fuses slice-merge + inclusive scan (ref & tmpl)
// + histogram-matching LUT build, all in LDS (64KB cum arrays, swizzled).
__global__ __launch_bounds__(256) void fused_scan_lut_kernel(
    const unsigned* __restrict__ partials, float* __restrict__ lut, int bpt)
{
    __shared__ unsigned cumR[NBINS];
    __shared__ unsigned cumT[NBINS];
    __shared__ unsigned totR[256], totT[256];
    int ch = blockIdx.x;
    int t  = threadIdx.x;
    const int items = NBINS / 256;    // 32

    // Phase A: merge bpt slices, coalesced (bin = i*256 + t), write swizzled
    const unsigned* pR = partials + (size_t)ch * bpt * NBINS;          // ref
    const unsigned* pT = partials + (size_t)(NCH + ch) * bpt * NBINS;  // tmpl
    for (int i = 0; i < items; ++i) {
        int bin = i * 256 + t;
        unsigned vR = 0, vT = 0;
        for (int k = 0; k < bpt; ++k) {
            vR += pR[(size_t)k * NBINS + bin];
            vT += pT[(size_t)k * NBINS + bin];
        }
        cumR[sidx(bin)] = vR;
        cumT[sidx(bin)] = vT;
    }
    __syncthreads();

    // Phase B: serial prefix over contiguous chunk per thread
    unsigned runR = 0, runT = 0;
    for (int i = 0; i < items; ++i) {
        int bin = t * items + i;
        runR += cumR[sidx(bin)]; cumR[sidx(bin)] = runR;
        runT += cumT[sidx(bin)]; cumT[sidx(bin)] = runT;
    }
    totR[t] = runR; totT[t] = runT;
    __syncthreads();
    for (int off = 1; off < 256; off <<= 1) {
        unsigned vR = (t >= off) ? totR[t - off] : 0u;
        unsigned vT = (t >= off) ? totT[t - off] : 0u;
        __syncthreads();
        totR[t] += vR; totT[t] += vT;
        __syncthreads();
    }
    unsigned exR = totR[t] - runR, exT = totT[t] - runT;
    for (int i = 0; i < items; ++i) {
        int bin = t * items + i;
        cumR[sidx(bin)] += exR;
        cumT[sidx(bin)] += exT;
    }
    __syncthreads();

    // Phase C: LUT build. bin = i*256 + t for coalesced global writes.
    float* lrow = lut + (size_t)ch * NBINS;
    for (int i = 0; i < items; ++i) {
        int bin = i * 256 + t;
        unsigned r    = cumR[sidx(bin)];
        unsigned prev = bin ? cumR[sidx(bin - 1)] : 0u;
        float val = 0.0f;                         // empty ref bin: unused
        if (r != prev) {
            int loi = 0, hii = NBINS;             // lower_bound(cumT, r)
            while (loi < hii) {
                int mid = (loi + hii) >> 1;
                if (cumT[sidx(mid)] < r) loi = mid + 1; else hii = mid;
            }
            int j = loi;
            unsigned cj    = cumT[sidx(j)];
            unsigned cprev = j ? cumT[sidx(j - 1)] : 0u;
            unsigned cnt   = cj - cprev;          // >= 1
            float frac = ((float)(r - cprev) - 0.5f) / (float)cnt;
            val = LO_ + ((float)j + frac) * BINW;
        }
        lrow[bin] = val;
    }
}

__global__ __launch_bounds__(256) void loss_kernel(
    const float* __restrict__ src, const float* __restrict__ ref,
    const float* __restrict__ smask, const float* __restrict__ lut,
    double* __restrict__ partials)
{
    const float4* src4 = (const float4*)src;
    const float4* ref4 = (const float4*)ref;
    const float4* sm4  = (const float4*)smask;
    const int N4 = TOTAL / 4;
    int stride = gridDim.x * blockDim.x;
    double acc = 0.0;
    for (int i = blockIdx.x * 256 + threadIdx.x; i < N4; i += stride) {
        int ch = i >> (HW_SHIFT - 2);
        int p4 = i & ((HW_ >> 2) - 1);
        int mb = ch / 3;
        float4 m  = sm4[((size_t)mb << (HW_SHIFT - 2)) + p4];
        float4 rv = ref4[i];
        float4 sv = src4[i];
        const float* lrow = lut + (size_t)ch * NBINS;
        float d0 = m.x * (t2i(sv.x) - lrow[bin_of(t2i(rv.x) * m.x)]);
        float d1 = m.y * (t2i(sv.y) - lrow[bin_of(t2i(rv.y) * m.y)]);
        float d2 = m.z * (t2i(sv.z) - lrow[bin_of(t2i(rv.z) * m.z)]);
        float d3 = m.w * (t2i(sv.w) - lrow[bin_of(t2i(rv.w) * m.w)]);
        acc += (double)d0 * d0 + (double)d1 * d1
             + (double)d2 * d2 + (double)d3 * d3;
    }
    __shared__ double sred[256];
    sred[threadIdx.x] = acc;
    __syncthreads();
    for (int off = 128; off > 0; off >>= 1) {
        if (threadIdx.x < off) sred[threadIdx.x] += sred[threadIdx.x + off];
        __syncthreads();
    }
    if (threadIdx.x == 0) partials[blockIdx.x] = sred[0];
}

__global__ __launch_bounds__(256) void finalize_kernel(
    const double* __restrict__ partials, int n, float* __restrict__ out)
{
    __shared__ double sred[256];
    double acc = 0.0;
    for (int i = threadIdx.x; i < n; i += 256) acc += partials[i];
    sred[threadIdx.x] = acc;
    __syncthreads();
    for (int off = 128; off > 0; off >>= 1) {
        if (threadIdx.x < off) sred[threadIdx.x] += sred[threadIdx.x + off];
        __syncthreads();
    }
    if (threadIdx.x == 0) out[0] = (float)(sred[0] / (double)TOTAL);
}

extern "C" void kernel_launch(void* const* d_in, const int* in_sizes, int n_in,
                              void* d_out, int out_size, void* d_ws, size_t ws_size,
                              hipStream_t stream) {
    const float* src   = (const float*)d_in[0];
    const float* tgt   = (const float*)d_in[1];
    const float* smask = (const float*)d_in[2];
    const float* tmask = (const float*)d_in[3];
    const float* ref   = (const float*)d_in[4];
    float* out = (float*)d_out;

    // workspace: [loss partials | lut | slice partials]
    size_t off = 0;
    double* lpart = (double*)d_ws;
    off += (size_t)LOSS_BLOCKS * sizeof(double);
    off = (off + 255) & ~(size_t)255;
    float* lut = (float*)((char*)d_ws + off);
    off += (size_t)NCH * NBINS * 4;

    int bpt = 8;  // 768 hist blocks; fall back if workspace is small
    while (bpt > 1 && off + (size_t)NTASK * bpt * NBINS * 4 > ws_size) bpt >>= 1;
    unsigned* partials = (unsigned*)((char*)d_ws + off);

    hist_kernel<<<NTASK * bpt, 512, 0, stream>>>(ref, tgt, smask, tmask,
                                                 partials, bpt);
    fused_scan_lut_kernel<<<NCH, 256, 0, stream>>>(partials, lut, bpt);
    loss_kernel<<<LOSS_BLOCKS, 256, 0, stream>>>(src, ref, smask, lut, lpart);
    finalize_kernel<<<1, 256, 0, stream>>>(lpart, LOSS_BLOCKS, out);
}

// Round 4
// 74.537 us; speedup vs baseline: 1.6371x; 1.6371x over previous
//
#include <hip/hip_runtime.h>

// Problem constants (B=16, C=3, H=W=512)
#define HW_SHIFT 18
#define HW_ (1 << HW_SHIFT)           // 262144
#define NCH 48                         // B*C
#define NTASK (2 * NCH)                // 96: ref-hist and tgt-hist per channel
#define TOTAL (NCH * HW_)              // 12,582,912
#define NBINS 8192                     // 32KB LDS histogram
#define LO_ (-640.0f)
#define HI_ (896.0f)
#define BINW ((HI_ - LO_) / (float)NBINS)
#define INVW ((float)NBINS / (HI_ - LO_))
#define LOSS_BLOCKS 2048

__device__ __forceinline__ float t2i(float x) { return fmaf(x, 127.5f, 127.5f); }

__device__ __forceinline__ int bin_of(float v) {
    int b = (int)((v - LO_) * INVW);
    b = b < 0 ? 0 : b;
    b = b > NBINS - 1 ? NBINS - 1 : b;
    return b;
}

// grid = NTASK*bpt blocks of 512. task = blockIdx.x/bpt; which = task/NCH
// (0 = ref/smask, 1 = tgt/tmask); ch = task%NCH. Each block histograms
// HW_/bpt pixels into a 32KB LDS histogram, then plain-stores the partial.
__global__ __launch_bounds__(512) void hist_kernel(
    const float* __restrict__ ref, const float* __restrict__ tgt,
    const float* __restrict__ smask, const float* __restrict__ tmask,
    unsigned* __restrict__ partials, int bpt)
{
    __shared__ unsigned lh[NBINS];
    for (int i = threadIdx.x; i < NBINS; i += 512) lh[i] = 0u;
    __syncthreads();

    int task  = blockIdx.x / bpt;
    int slice = blockIdx.x - task * bpt;
    int which = task / NCH;
    int ch    = task - which * NCH;
    const float* img = which ? tgt : ref;
    const float* msk = which ? tmask : smask;
    int mb = ch / 3;

    const float4* img4 = (const float4*)img + ((size_t)ch << (HW_SHIFT - 2));
    const float4* msk4 = (const float4*)msk + ((size_t)mb << (HW_SHIFT - 2));
    int n4   = (HW_ / 4) / bpt;       // 8192 at bpt=8 (divisible by 1024)
    int base = slice * n4;
    for (int i = threadIdx.x; i < n4; i += 1024) {
        float4 v0 = img4[base + i];
        float4 m0 = msk4[base + i];
        float4 v1 = img4[base + i + 512];
        float4 m1 = msk4[base + i + 512];
        atomicAdd(&lh[bin_of(t2i(v0.x) * m0.x)], 1u);
        atomicAdd(&lh[bin_of(t2i(v0.y) * m0.y)], 1u);
        atomicAdd(&lh[bin_of(t2i(v0.z) * m0.z)], 1u);
        atomicAdd(&lh[bin_of(t2i(v0.w) * m0.w)], 1u);
        atomicAdd(&lh[bin_of(t2i(v1.x) * m1.x)], 1u);
        atomicAdd(&lh[bin_of(t2i(v1.y) * m1.y)], 1u);
        atomicAdd(&lh[bin_of(t2i(v1.z) * m1.z)], 1u);
        atomicAdd(&lh[bin_of(t2i(v1.w) * m1.w)], 1u);
    }
    __syncthreads();
    unsigned* outp = partials + (size_t)blockIdx.x * NBINS;
    for (int i = threadIdx.x; i < NBINS; i += 512) outp[i] = lh[i];
}

// hist2[t*NBINS+b] = sum over bpt slices. Rows 0..47 = ref hists, 48..95 = tmpl.
__global__ __launch_bounds__(256) void merge_kernel(
    const unsigned* __restrict__ partials, unsigned* __restrict__ hist2, int bpt)
{
    int i = blockIdx.x * 256 + threadIdx.x;
    if (i >= NTASK * NBINS) return;
    int task = i / NBINS;
    int bin  = i - task * NBINS;
    unsigned s = 0;
    for (int k = 0; k < bpt; ++k)
        s += partials[((size_t)(task * bpt + k)) * NBINS + bin];
    hist2[i] = s;
}

template <int T>
__device__ void scan_row(unsigned* __restrict__ row) {
    __shared__ unsigned tot[T];
    int t = threadIdx.x;
    const int items = NBINS / T;
    unsigned* base = row + t * items;
    unsigned run = 0;
    for (int i = 0; i < items; ++i) { run += base[i]; base[i] = run; }
    tot[t] = run;
    __syncthreads();
    for (int off = 1; off < T; off <<= 1) {
        unsigned v = (t >= off) ? tot[t - off] : 0u;
        __syncthreads();
        tot[t] += v;
        __syncthreads();
    }
    unsigned excl = tot[t] - run;
    for (int i = 0; i < items; ++i) base[i] += excl;
}

// grid = NTASK blocks, one cumulative row per block.
__global__ __launch_bounds__(256) void scan_kernel(unsigned* __restrict__ hist2)
{
    scan_row<256>(hist2 + (size_t)blockIdx.x * NBINS);
}

__global__ __launch_bounds__(256) void lut_kernel(
    const unsigned* __restrict__ hist2, float* __restrict__ lut)
{
    int stride = gridDim.x * blockDim.x;
    const int total = NCH * NBINS;
    for (int i = blockIdx.x * 256 + threadIdx.x; i < total; i += stride) {
        int ch  = i / NBINS;
        int bin = i - ch * NBINS;
        unsigned r    = hist2[i];                    // cum_ref row ch
        unsigned prev = bin ? hist2[i - 1] : 0u;
        if (r == prev) { lut[i] = 0.0f; continue; }  // empty ref bin: unused
        const unsigned* row = hist2 + (size_t)(NCH + ch) * NBINS;  // cum_tmpl
        int loi = 0, hii = NBINS;                    // lower_bound(row, r)
        while (loi < hii) {
            int mid = (loi + hii) >> 1;
            if (row[mid] < r) loi = mid + 1; else hii = mid;
        }
        int j = loi;
        unsigned cj    = row[j];
        unsigned cprev = j ? row[j - 1] : 0u;
        unsigned cnt   = cj - cprev;                 // >= 1
        float frac = ((float)(r - cprev) - 0.5f) / (float)cnt;
        lut[i] = LO_ + ((float)j + frac) * BINW;
    }
}

__global__ __launch_bounds__(256) void loss_kernel(
    const float* __restrict__ src, const float* __restrict__ ref,
    const float* __restrict__ smask, const float* __restrict__ lut,
    double* __restrict__ partials)
{
    const float4* src4 = (const float4*)src;
    const float4* ref4 = (const float4*)ref;
    const float4* sm4  = (const float4*)smask;
    const int N4 = TOTAL / 4;
    int stride = gridDim.x * blockDim.x;
    double acc = 0.0;
    for (int i = blockIdx.x * 256 + threadIdx.x; i < N4; i += stride) {
        int ch = i >> (HW_SHIFT - 2);
        int p4 = i & ((HW_ >> 2) - 1);
        int mb = ch / 3;
        float4 m  = sm4[((size_t)mb << (HW_SHIFT - 2)) + p4];
        float4 rv = ref4[i];
        float4 sv = src4[i];
        const float* lrow = lut + (size_t)ch * NBINS;
        float d0 = m.x * (t2i(sv.x) - lrow[bin_of(t2i(rv.x) * m.x)]);
        float d1 = m.y * (t2i(sv.y) - lrow[bin_of(t2i(rv.y) * m.y)]);
        float d2 = m.z * (t2i(sv.z) - lrow[bin_of(t2i(rv.z) * m.z)]);
        float d3 = m.w * (t2i(sv.w) - lrow[bin_of(t2i(rv.w) * m.w)]);
        acc += (double)d0 * d0 + (double)d1 * d1
             + (double)d2 * d2 + (double)d3 * d3;
    }
    __shared__ double sred[256];
    sred[threadIdx.x] = acc;
    __syncthreads();
    for (int off = 128; off > 0; off >>= 1) {
        if (threadIdx.x < off) sred[threadIdx.x] += sred[threadIdx.x + off];
        __syncthreads();
    }
    if (threadIdx.x == 0) partials[blockIdx.x] = sred[0];
}

__global__ __launch_bounds__(256) void finalize_kernel(
    const double* __restrict__ partials, int n, float* __restrict__ out)
{
    __shared__ double sred[256];
    double acc = 0.0;
    for (int i = threadIdx.x; i < n; i += 256) acc += partials[i];
    sred[threadIdx.x] = acc;
    __syncthreads();
    for (int off = 128; off > 0; off >>= 1) {
        if (threadIdx.x < off) sred[threadIdx.x] += sred[threadIdx.x + off];
        __syncthreads();
    }
    if (threadIdx.x == 0) out[0] = (float)(sred[0] / (double)TOTAL);
}

extern "C" void kernel_launch(void* const* d_in, const int* in_sizes, int n_in,
                              void* d_out, int out_size, void* d_ws, size_t ws_size,
                              hipStream_t stream) {
    const float* src   = (const float*)d_in[0];
    const float* tgt   = (const float*)d_in[1];
    const float* smask = (const float*)d_in[2];
    const float* tmask = (const float*)d_in[3];
    const float* ref   = (const float*)d_in[4];
    float* out = (float*)d_out;

    // workspace: [loss partials | hist2 | lut | slice partials]
    size_t off = 0;
    double* lpart = (double*)d_ws;
    off += (size_t)LOSS_BLOCKS * sizeof(double);
    off = (off + 255) & ~(size_t)255;
    unsigned* hist2 = (unsigned*)((char*)d_ws + off);
    off += (size_t)NTASK * NBINS * 4;
    float* lut = (float*)((char*)d_ws + off);
    off += (size_t)NCH * NBINS * 4;

    int bpt = 8;  // 768 hist blocks; fall back if workspace is small
    while (bpt > 1 && off + (size_t)NTASK * bpt * NBINS * 4 > ws_size) bpt >>= 1;
    unsigned* partials = (unsigned*)((char*)d_ws + off);

    hist_kernel<<<NTASK * bpt, 512, 0, stream>>>(ref, tgt, smask, tmask,
                                                 partials, bpt);
    merge_kernel<<<(NTASK * NBINS + 255) / 256, 256, 0, stream>>>(partials,
                                                                  hist2, bpt);
    scan_kernel<<<NTASK, 256, 0, stream>>>(hist2);
    lut_kernel<<<(NCH * NBINS + 255) / 256, 256, 0, stream>>>(hist2, lut);
    loss_kernel<<<LOSS_BLOCKS, 256, 0, stream>>>(src, ref, smask, lut, lpart);
    finalize_kernel<<<1, 256, 0, stream>>>(lpart, LOSS_BLOCKS, out);
}